// Round 6
// baseline (4377.474 us; speedup 1.0000x reference)
//
#include <hip/hip_runtime.h>
#include <stdint.h>

// TrajEncoder: embedding gather + LSTM(D=128,H=256) over T=512, output h at valid_len-1.
// R6: ONE WG (1024 threads) per batch, 64 WGs total. ALL weights (1024x384 f16-packed)
// live in the WG's registers (192 VGPRs/thread); h/x broadcast via LDS + barriers only.
// No inter-WG exchange, no spin loops, no workspace.
// R5->R6 fix: 8-lane reduce's 3rd hop uses row_half_mirror (0x141, symmetric => rotate-
// direction-proof) instead of row_ror:4 (direction-ambiguous; R5's absmax 0.63 matched
// the wrong-direction signature: lane0 summed quad0+quad3 across row groups).

#define BB 64
#define TT 512
#define DD 128
#define HH 256

typedef __fp16 half2v __attribute__((ext_vector_type(2)));

__device__ __forceinline__ uint32_t pk_f16(float lo, float hi) {
    half2v h = __builtin_amdgcn_cvt_pkrtz(lo, hi);
    return __builtin_bit_cast(uint32_t, h);
}

__device__ __forceinline__ float dot2(uint32_t a, uint32_t b, float acc) {
#if __has_builtin(__builtin_amdgcn_fdot2)
    return __builtin_amdgcn_fdot2(__builtin_bit_cast(half2v, a),
                                  __builtin_bit_cast(half2v, b), acc, false);
#else
    half2v av = __builtin_bit_cast(half2v, a);
    half2v bv = __builtin_bit_cast(half2v, b);
    acc += (float)av[0] * (float)bv[0];
    acc += (float)av[1] * (float)bv[1];
    return acc;
#endif
}

// a += a[perm(lane)] via DPP. 0xB1=quad xor1, 0x4E=quad xor2,
// 0x141=row_half_mirror (p <-> 7-p within each 8-lane half-row; symmetric).
// After the 3-hop chain ALL 8 lanes of each half-row hold the 8-lane sum.
template<int CTRL>
__device__ __forceinline__ float dpp_add(float a) {
    int m = __builtin_amdgcn_update_dpp(0, __builtin_bit_cast(int, a), CTRL, 0xF, 0xF, false);
    return a + __builtin_bit_cast(float, m);
}

__device__ __forceinline__ float fsig(float x)  { return 1.f / (1.f + __expf(-x)); }
__device__ __forceinline__ float ftanh(float x) { return 1.f - 2.f / (__expf(2.f * x) + 1.f); }

__global__ __launch_bounds__(1024, 4)
void lstm_solo_kernel(const int* __restrict__ path, const int* __restrict__ vlen,
                      const float* __restrict__ emb, const float* __restrict__ Wih,
                      const float* __restrict__ Whh, const float* __restrict__ bih,
                      const float* __restrict__ bhh, float* __restrict__ out) {
    const int b   = blockIdx.x;        // one batch per WG
    const int tid = threadIdx.x;
    const int cg  = tid & 7;           // col-group: h cols [32cg,32cg+32), x cols [16cg,16cg+16)
    const int rb  = tid >> 3;          // row-block 0..127: gate rows [8rb, 8rb+8)

    __shared__ uint32_t h_pk[8][24];     // packed h: 16 u32 used/row, stride 96B (16B-aligned)
    __shared__ uint32_t x_pk[2][8][12];  // packed x_t double-buffered: 8 u32 used/row, stride 48B
    __shared__ float    G[1024];         // gate pre-activations (no bias)
    __shared__ int      path_l[TT];

    // ---- full weight matrix -> registers: 8 rows x (16 h-u32 + 8 x-u32) per thread ----
    uint32_t whh[128];
    uint32_t wih[64];
#pragma unroll
    for (int rr = 0; rr < 8; ++rr) {
        const int row = (rb << 3) + rr;                 // global gate row 0..1023 (i,f,g,o order)
        const float* wr = Whh + row * HH + (cg << 5);
#pragma unroll
        for (int c = 0; c < 16; ++c) whh[rr * 16 + c] = pk_f16(wr[2 * c], wr[2 * c + 1]);
        const float* wr2 = Wih + row * DD + (cg << 4);
#pragma unroll
        for (int c = 0; c < 8; ++c) wih[rr * 8 + c] = pk_f16(wr2[2 * c], wr2[2 * c + 1]);
    }
    const int L = vlen[b];

    // biases for the pointwise threads (unit = tid < 256)
    float bi = 0.f, bf = 0.f, bg = 0.f, bo = 0.f;
    if (tid < HH) {
        bi = bih[tid]       + bhh[tid];
        bf = bih[256 + tid] + bhh[256 + tid];
        bg = bih[512 + tid] + bhh[512 + tid];
        bo = bih[768 + tid] + bhh[768 + tid];
    }

    if (tid < TT)  path_l[tid] = path[b * TT + tid];
    if (tid < 192) ((uint32_t*)h_pk)[tid] = 0u;        // h_0 = 0 (pads included)
    __syncthreads();

    // x pipeline (threads 256..383 = waves 4,5): stage x_0, prefetch x_1
    float xr_next = 0.f;
    if (tid >= 256 && tid < 384) {
        int e = tid - 256;
        float x0  = emb[(size_t)path_l[0] * DD + e];
        float x0h = __shfl_xor(x0, 1);
        if (!(e & 1)) x_pk[0][e >> 4][(e >> 1) & 7] = pk_f16(x0, x0h);
        xr_next = emb[(size_t)path_l[L > 1 ? 1 : 0] * DD + e];
    }
    float c_state = 0.f;
    __syncthreads();

    for (int t = 0; t < L; ++t) {
        const int slot = t & 1;

        // ---- dots: 8 rows x (32 h + 16 x cols); LDS = 6 x ds_read_b128/thread ----
        const uint4 hv0 = *(const uint4*)&h_pk[cg][0];
        const uint4 hv1 = *(const uint4*)&h_pk[cg][4];
        const uint4 hv2 = *(const uint4*)&h_pk[cg][8];
        const uint4 hv3 = *(const uint4*)&h_pk[cg][12];
        const uint4 xv0 = *(const uint4*)&x_pk[slot][cg][0];
        const uint4 xv1 = *(const uint4*)&x_pk[slot][cg][4];
        float acc[8];
#pragma unroll
        for (int rr = 0; rr < 8; ++rr) {
            float a = 0.f;
            a = dot2(whh[rr * 16 +  0], hv0.x, a);
            a = dot2(whh[rr * 16 +  1], hv0.y, a);
            a = dot2(whh[rr * 16 +  2], hv0.z, a);
            a = dot2(whh[rr * 16 +  3], hv0.w, a);
            a = dot2(whh[rr * 16 +  4], hv1.x, a);
            a = dot2(whh[rr * 16 +  5], hv1.y, a);
            a = dot2(whh[rr * 16 +  6], hv1.z, a);
            a = dot2(whh[rr * 16 +  7], hv1.w, a);
            a = dot2(whh[rr * 16 +  8], hv2.x, a);
            a = dot2(whh[rr * 16 +  9], hv2.y, a);
            a = dot2(whh[rr * 16 + 10], hv2.z, a);
            a = dot2(whh[rr * 16 + 11], hv2.w, a);
            a = dot2(whh[rr * 16 + 12], hv3.x, a);
            a = dot2(whh[rr * 16 + 13], hv3.y, a);
            a = dot2(whh[rr * 16 + 14], hv3.z, a);
            a = dot2(whh[rr * 16 + 15], hv3.w, a);
            a = dot2(wih[rr * 8 + 0], xv0.x, a);
            a = dot2(wih[rr * 8 + 1], xv0.y, a);
            a = dot2(wih[rr * 8 + 2], xv0.z, a);
            a = dot2(wih[rr * 8 + 3], xv0.w, a);
            a = dot2(wih[rr * 8 + 4], xv1.x, a);
            a = dot2(wih[rr * 8 + 5], xv1.y, a);
            a = dot2(wih[rr * 8 + 6], xv1.z, a);
            a = dot2(wih[rr * 8 + 7], xv1.w, a);
            // 8-lane reduce: quad xor1, quad xor2, half-row mirror (direction-proof)
            a = dpp_add<0xB1>(a);
            a = dpp_add<0x4E>(a);
            a = dpp_add<0x141>(a);
            acc[rr] = a;
        }
        if (cg == 0) {
            *(float4*)&G[(rb << 3) + 0] = make_float4(acc[0], acc[1], acc[2], acc[3]);
            *(float4*)&G[(rb << 3) + 4] = make_float4(acc[4], acc[5], acc[6], acc[7]);
        }
        __syncthreads();

        // ---- role phase: waves 0-3 pointwise | waves 4-5 x staging ----
        if (tid < HH) {
            float gi = fsig(G[tid] + bi);
            float gf = fsig(G[256 + tid] + bf);
            float gg = ftanh(G[512 + tid] + bg);
            float go = fsig(G[768 + tid] + bo);
            c_state  = gf * c_state + gi * gg;
            float h  = go * ftanh(c_state);
            if (t == L - 1) out[b * HH + tid] = h;
            float h1 = __shfl_xor(h, 1);
            if (!(tid & 1)) {
                int j = tid >> 1;                       // u32 index 0..127
                h_pk[j >> 4][j & 15] = pk_f16(h, h1);
            }
        } else if (tid >= 256 && tid < 384) {
            int e = tid - 256;
            float xh = __shfl_xor(xr_next, 1);
            if (!(e & 1)) x_pk[slot ^ 1][e >> 4][(e >> 1) & 7] = pk_f16(xr_next, xh);
            int tpf = (t + 2 < TT) ? t + 2 : TT - 1;
            xr_next = emb[(size_t)path_l[tpf] * DD + e];   // prefetch x_{t+2}
        }
        __syncthreads();   // h_pk / x_pk ready for next step
    }
}

extern "C" void kernel_launch(void* const* d_in, const int* in_sizes, int n_in,
                              void* d_out, int out_size, void* d_ws, size_t ws_size,
                              hipStream_t stream) {
    const int*   path = (const int*)d_in[0];
    const int*   vlen = (const int*)d_in[1];
    const float* emb  = (const float*)d_in[2];
    const float* Wih  = (const float*)d_in[3];
    const float* Whh  = (const float*)d_in[4];
    const float* bih  = (const float*)d_in[5];
    const float* bhh  = (const float*)d_in[6];

    lstm_solo_kernel<<<BB, 1024, 0, stream>>>(path, vlen, emb, Wih, Whh, bih, bhh,
                                              (float*)d_out);
}

// Round 7
// 1284.297 us; speedup vs baseline: 3.4085x; 3.4085x over previous
//
#include <hip/hip_runtime.h>
#include <stdint.h>

// TrajEncoder: embedding gather + LSTM(D=128,H=256) over T=512, output h at valid_len-1.
// R7: 2 WGs (512 thr) per batch, paired AT RUNTIME on the same XCD via HW_REG_XCC_ID +
// per-XCD rank claiming -> h-exchange goes through the shared per-XCD L2 with sc0
// (L1-bypass) loads/stores, RTT ~200-300 cyc instead of ~2500 (cross-XCD L3 agent path).
// Bounded sc0 poll with permanent agent-scope fallback = R3-correctness worst case.
// Weights: each WG holds its 512 gate rows f16-packed in registers (192 u32/thread,
// 256-VGPR budget via __launch_bounds__(512,2) -- R6's spill fiasco was a 128-cap).
// Epoch encoding: h in (-1,1) => bit14 of each f16 half clear; ~pk sets it; memset 0xFF
// rejects at phase-0 steps. 8-lane DPP reduce uses row_half_mirror (R6-proven).

#define BB 64
#define TT 512
#define DD 128
#define HH 256

// ws layout (u32 units)
#define WS_BCNT   0        // [0]       global batch counter
#define WS_RANK   8        // [8..16)   per-XCD rank counters
#define WS_TABLE  16       // [16..1040) per-XCD pair->batch+1 table (8 x 128)
#define WS_EXC    2048     // sc0 exchange [2][BB][128]; then agent region same size

typedef __fp16 half2v __attribute__((ext_vector_type(2)));

__device__ __forceinline__ uint32_t pk_f16(float lo, float hi) {
    half2v h = __builtin_amdgcn_cvt_pkrtz(lo, hi);
    return __builtin_bit_cast(uint32_t, h);
}

__device__ __forceinline__ float dot2(uint32_t a, uint32_t b, float acc) {
    return __builtin_amdgcn_fdot2(__builtin_bit_cast(half2v, a),
                                  __builtin_bit_cast(half2v, b), acc, false);
}

// a += a[perm(lane)] via DPP. 0xB1=quad xor1, 0x4E=quad xor2, 0x141=row_half_mirror
// (p <-> 7-p within each 8-lane half-row; symmetric => rotate-direction-proof).
template<int CTRL>
__device__ __forceinline__ float dpp_add(float a) {
    int m = __builtin_amdgcn_update_dpp(0, __builtin_bit_cast(int, a), CTRL, 0xF, 0xF, false);
    return a + __builtin_bit_cast(float, m);
}

// L1-bypass, L2-coherent (same-XCD) ops.
__device__ __forceinline__ uint32_t load_sc0(const uint32_t* p) {
    uint32_t v;
    asm volatile("global_load_dword %0, %1, off sc0\n\ts_waitcnt vmcnt(0)"
                 : "=v"(v) : "v"(p) : "memory");
    return v;
}
__device__ __forceinline__ void store_sc0(uint32_t* p, uint32_t v) {
    asm volatile("global_store_dword %0, %1, off sc0" :: "v"(p), "v"(v) : "memory");
}

__device__ __forceinline__ float fsig(float x)  { return 1.f / (1.f + __expf(-x)); }
__device__ __forceinline__ float ftanh(float x) { return 1.f - 2.f / (__expf(2.f * x) + 1.f); }

__global__ __launch_bounds__(512, 2)
void lstm_pair_kernel(const int* __restrict__ path, const int* __restrict__ vlen,
                      const float* __restrict__ emb, const float* __restrict__ Wih,
                      const float* __restrict__ Whh, const float* __restrict__ bih,
                      const float* __restrict__ bhh, float* __restrict__ out,
                      uint32_t* ctl) {
    uint32_t* excF = ctl + WS_EXC;              // sc0 region
    uint32_t* excA = excF + 2 * BB * 128;       // agent fallback region
    const int tid = threadIdx.x;

    // ---- runtime same-XCD pairing: rank within XCD; even rank claims a batch ----
    __shared__ int s_bh;
    if (tid == 0) {
        uint32_t xcc;
        asm volatile("s_getreg_b32 %0, hwreg(20, 0, 4)" : "=s"(xcc));  // HW_REG_XCC_ID
        int rank = __hip_atomic_fetch_add((int*)&ctl[WS_RANK + xcc], 1,
                                          __ATOMIC_RELAXED, __HIP_MEMORY_SCOPE_AGENT);
        int pair = rank >> 1, half = rank & 1;
        int batch = BB;
        if (pair < 128) {
            int* tslot = (int*)&ctl[WS_TABLE + xcc * 128 + pair];
            if (half == 0) {
                batch = __hip_atomic_fetch_add((int*)&ctl[WS_BCNT], 1,
                                               __ATOMIC_RELAXED, __HIP_MEMORY_SCOPE_AGENT);
                __hip_atomic_store(tslot, batch + 1, __ATOMIC_RELAXED,
                                   __HIP_MEMORY_SCOPE_AGENT);
            } else {
                // partner (rank-1, same XCD) exists and always publishes -> safe wait
                int v;
                do {
                    v = __hip_atomic_load(tslot, __ATOMIC_RELAXED, __HIP_MEMORY_SCOPE_AGENT);
                    if (!v) __builtin_amdgcn_s_sleep(2);
                } while (!v);
                batch = v - 1;
            }
        }
        s_bh = (batch << 1) | half;
    }
    __syncthreads();
    const int b    = s_bh >> 1;
    const int half = s_bh & 1;          // owns h units [128*half, 128*half+128)
    if (b >= BB) return;                // surplus WG

    const int cg = tid & 7;             // col-group: h cols [32cg,32cg+32), x cols [16cg,16cg+16)
    const int rb = tid >> 3;            // row-block 0..63: local gate rows [8rb, 8rb+8)

    __shared__ uint32_t h_pk[8][24];    // full packed h (128 u32 used + pad)
    __shared__ uint32_t x_pk[2][8][12]; // packed x_t, double buffered (64 u32 used + pad)
    __shared__ float    G[512];         // our 512 gate pre-activations
    __shared__ int      path_l[TT];

    // ---- weight slices -> registers: 8 local rows x (16 h-u32 + 8 x-u32) ----
    uint32_t whh[128], wih[64];
#pragma unroll
    for (int rr = 0; rr < 8; ++rr) {
        const int lr   = (rb << 3) + rr;                        // local row 0..511
        const int grow = ((lr >> 7) << 8) + (half << 7) + (lr & 127);  // global gate row
        const float* wr = Whh + grow * HH + (cg << 5);
#pragma unroll
        for (int c = 0; c < 16; ++c) whh[rr * 16 + c] = pk_f16(wr[2 * c], wr[2 * c + 1]);
        const float* wr2 = Wih + grow * DD + (cg << 4);
#pragma unroll
        for (int c = 0; c < 8; ++c) wih[rr * 8 + c] = pk_f16(wr2[2 * c], wr2[2 * c + 1]);
    }
    const int L = vlen[b];

    float bi = 0.f, bf = 0.f, bg = 0.f, bo = 0.f;
    if (tid < 128) {
        int u = (half << 7) + tid;
        bi = bih[u]       + bhh[u];
        bf = bih[256 + u] + bhh[256 + u];
        bg = bih[512 + u] + bhh[512 + u];
        bo = bih[768 + u] + bhh[768 + u];
    }
    path_l[tid] = path[b * TT + tid];               // 512 threads == TT
    if (tid < 192) ((uint32_t*)h_pk)[tid] = 0u;     // h_0 = 0 (pads included)
    __syncthreads();

    // x pipeline (waves 6-7): stage x_0, prefetch x_1
    float xr_next = 0.f;
    if (tid >= 384) {
        int e = tid - 384;
        float x0  = emb[(size_t)path_l[0] * DD + e];
        float x0h = __shfl_xor(x0, 1);
        if (!(e & 1)) { int j = e >> 1; x_pk[0][j >> 3][j & 7] = pk_f16(x0, x0h); }
        xr_next = emb[(size_t)path_l[L > 1 ? 1 : 0] * DD + e];
    }
    float c_state = 0.f;
    bool  fast_ok = true;
    __syncthreads();

    for (int t = 0; t < L; ++t) {
        const int slot  = t & 1;
        const int phase = (t >> 1) & 1;
        const uint32_t want = phase ? 0x40004000u : 0u;

        // ---- dots: 8 rows x (32 h + 16 x cols) = 24 dot2/row; LDS = 6 b128/thread ----
        const uint4 hv0 = *(const uint4*)&h_pk[cg][0];
        const uint4 hv1 = *(const uint4*)&h_pk[cg][4];
        const uint4 hv2 = *(const uint4*)&h_pk[cg][8];
        const uint4 hv3 = *(const uint4*)&h_pk[cg][12];
        const uint4 xv0 = *(const uint4*)&x_pk[slot][cg][0];
        const uint4 xv1 = *(const uint4*)&x_pk[slot][cg][4];
        float acc[8];
#pragma unroll
        for (int rr = 0; rr < 8; ++rr) {
            float a = 0.f;
            a = dot2(whh[rr * 16 +  0], hv0.x, a);
            a = dot2(whh[rr * 16 +  1], hv0.y, a);
            a = dot2(whh[rr * 16 +  2], hv0.z, a);
            a = dot2(whh[rr * 16 +  3], hv0.w, a);
            a = dot2(whh[rr * 16 +  4], hv1.x, a);
            a = dot2(whh[rr * 16 +  5], hv1.y, a);
            a = dot2(whh[rr * 16 +  6], hv1.z, a);
            a = dot2(whh[rr * 16 +  7], hv1.w, a);
            a = dot2(whh[rr * 16 +  8], hv2.x, a);
            a = dot2(whh[rr * 16 +  9], hv2.y, a);
            a = dot2(whh[rr * 16 + 10], hv2.z, a);
            a = dot2(whh[rr * 16 + 11], hv2.w, a);
            a = dot2(whh[rr * 16 + 12], hv3.x, a);
            a = dot2(whh[rr * 16 + 13], hv3.y, a);
            a = dot2(whh[rr * 16 + 14], hv3.z, a);
            a = dot2(whh[rr * 16 + 15], hv3.w, a);
            a = dot2(wih[rr * 8 + 0], xv0.x, a);
            a = dot2(wih[rr * 8 + 1], xv0.y, a);
            a = dot2(wih[rr * 8 + 2], xv0.z, a);
            a = dot2(wih[rr * 8 + 3], xv0.w, a);
            a = dot2(wih[rr * 8 + 4], xv1.x, a);
            a = dot2(wih[rr * 8 + 5], xv1.y, a);
            a = dot2(wih[rr * 8 + 6], xv1.z, a);
            a = dot2(wih[rr * 8 + 7], xv1.w, a);
            a = dpp_add<0xB1>(a);
            a = dpp_add<0x4E>(a);
            a = dpp_add<0x141>(a);
            acc[rr] = a;
        }
        if (cg == 0) {
            *(float4*)&G[(rb << 3) + 0] = make_float4(acc[0], acc[1], acc[2], acc[3]);
            *(float4*)&G[(rb << 3) + 4] = make_float4(acc[4], acc[5], acc[6], acc[7]);
        }
        __syncthreads();

        // ---- roles: waves0-1 pointwise+publish | wave5 poll | waves6-7 x staging ----
        if (tid < 128) {
            float gi = fsig(G[tid] + bi);
            float gf = fsig(G[128 + tid] + bf);
            float gg = ftanh(G[256 + tid] + bg);
            float go = fsig(G[384 + tid] + bo);
            c_state  = gf * c_state + gi * gg;
            float h  = go * ftanh(c_state);
            if (t == L - 1) out[b * HH + (half << 7) + tid] = h;
            float h1 = __shfl_xor(h, 1);
            if (!(tid & 1)) {
                uint32_t pk = pk_f16(h, h1);
                int j = (half << 6) + (tid >> 1);            // global u32 idx 0..127
                h_pk[j >> 4][j & 15] = pk;                   // own slice via LDS
                uint32_t enc = phase ? ~pk : pk;
                int idx = (slot * BB + b) * 128 + j;
                store_sc0(excF + idx, enc);                  // same-XCD L2 path
                __hip_atomic_store(excA + idx, enc,
                                   __ATOMIC_RELAXED, __HIP_MEMORY_SCOPE_AGENT);
            }
        } else if (tid >= 320 && tid < 384) {
            if (t < L - 1) {
                int c = tid - 320;                           // 64 peer u32s
                int j = ((1 - half) << 6) + c;
                const int idx = (slot * BB + b) * 128 + j;
                uint32_t v; bool got = false;
                if (fast_ok) {
                    int bound = (t == 0) ? 4000 : 600;
                    do {
                        v = load_sc0(excF + idx);
                        got = ((v & 0x40004000u) == want);
                    } while (!got && --bound);
                    if (!got) fast_ok = false;               // permanent fallback
                }
                if (!got) {
                    int spins = 0;
                    do {
                        v = __hip_atomic_load(excA + idx, __ATOMIC_RELAXED,
                                              __HIP_MEMORY_SCOPE_AGENT);
                    } while ((v & 0x40004000u) != want && ++spins < (1 << 20));
                }
                uint32_t d = phase ? ~v : v;
                h_pk[j >> 4][j & 15] = d;
            }
        } else if (tid >= 384) {
            int e = tid - 384;
            float xh = __shfl_xor(xr_next, 1);
            if (!(e & 1)) { int j = e >> 1; x_pk[slot ^ 1][j >> 3][j & 7] = pk_f16(xr_next, xh); }
            int tpf = (t + 2 < TT) ? t + 2 : TT - 1;
            xr_next = emb[(size_t)path_l[tpf] * DD + e];     // prefetch x_{t+2}
        }
        __syncthreads();
    }
}

extern "C" void kernel_launch(void* const* d_in, const int* in_sizes, int n_in,
                              void* d_out, int out_size, void* d_ws, size_t ws_size,
                              hipStream_t stream) {
    const int*   path = (const int*)d_in[0];
    const int*   vlen = (const int*)d_in[1];
    const float* emb  = (const float*)d_in[2];
    const float* Wih  = (const float*)d_in[3];
    const float* Whh  = (const float*)d_in[4];
    const float* bih  = (const float*)d_in[5];
    const float* bhh  = (const float*)d_in[6];

    // control region (counters + pair table): zeroed every launch (captured in graph)
    (void)hipMemsetAsync(d_ws, 0x00, (size_t)WS_EXC * 4, stream);
    // exchange regions (sc0 + agent): 0xFF = bit14 set -> rejected by phase-0 predicate
    (void)hipMemsetAsync((char*)d_ws + (size_t)WS_EXC * 4, 0xFF,
                         (size_t)2 * 2 * BB * 128 * 4, stream);
    lstm_pair_kernel<<<256, 512, 0, stream>>>(path, vlen, emb, Wih, Whh, bih, bhh,
                                              (float*)d_out, (uint32_t*)d_ws);
}

// Round 8
// 1092.614 us; speedup vs baseline: 4.0064x; 1.1754x over previous
//
#include <hip/hip_runtime.h>
#include <stdint.h>

// TrajEncoder: embedding gather + LSTM(D=128,H=256) over T=512, output h at valid_len-1.
// R8: 2 WGs (512 thr) per batch, paired at runtime on the same XCD (HW_REG_XCC_ID +
// per-XCD rank) -> h-exchange via sc0 (L1-bypass, L2-coherent) loads/stores; bounded
// poll with permanent agent-scope fallback. Pairing is handshake-hardened: a batch is
// claimed only after both partners commit (hello), unmatched WGs pair via a global
// orphan pool (orphan count provably even) -> no dispatch-placement assumptions.
// Weights f16-packed in registers: 192 u32/thread. __launch_bounds__(512,1): empirically
// (R6/R7) the 2nd arg acts as minBlocksPerCU -> 1 block x 8 waves -> 2 waves/SIMD ->
// 256-VGPR budget (R7's (512,2) capped at 128 and spilled).
// Epoch encoding: h in (-1,1) => bit14 of each f16 half clear; ~pk sets it; 0xFF init
// rejects at phase-0. 8-lane DPP reduce: quad xor1, xor2, row_half_mirror (R6-proven).

#define BB 64
#define TT 512
#define DD 128
#define HH 256

// ws layout (u32 units)
#define WS_BCNT   0        // global batch counter
#define WS_OCNT   1        // global orphan counter
#define WS_RANK   8        // [8..16) per-XCD rank counters
#define WS_HELLO  64       // [64..576)   per-XCD pair hello (8 x 64)
#define WS_BTAB   576      // [576..1088) per-XCD pair->batch+1 / -1=abandoned (8 x 64)
#define WS_OHELLO 1600     // [1600..1664) orphan hello
#define WS_OBTAB  1664     // [1664..1728) orphan pair->batch+1
#define WS_EXC    2048     // sc0 exchange [2][BB][128]; then agent region same size

typedef __fp16 half2v __attribute__((ext_vector_type(2)));

__device__ __forceinline__ uint32_t pk_f16(float lo, float hi) {
    half2v h = __builtin_amdgcn_cvt_pkrtz(lo, hi);
    return __builtin_bit_cast(uint32_t, h);
}

__device__ __forceinline__ float dot2(uint32_t a, uint32_t b, float acc) {
    return __builtin_amdgcn_fdot2(__builtin_bit_cast(half2v, a),
                                  __builtin_bit_cast(half2v, b), acc, false);
}

template<int CTRL>
__device__ __forceinline__ float dpp_add(float a) {
    int m = __builtin_amdgcn_update_dpp(0, __builtin_bit_cast(int, a), CTRL, 0xF, 0xF, false);
    return a + __builtin_bit_cast(float, m);
}

__device__ __forceinline__ uint32_t load_sc0(const uint32_t* p) {
    uint32_t v;
    asm volatile("global_load_dword %0, %1, off sc0\n\ts_waitcnt vmcnt(0)"
                 : "=v"(v) : "v"(p) : "memory");
    return v;
}
__device__ __forceinline__ void store_sc0(uint32_t* p, uint32_t v) {
    asm volatile("global_store_dword %0, %1, off sc0" :: "v"(p), "v"(v) : "memory");
}

__device__ __forceinline__ int a_ld(int* p) {
    return __hip_atomic_load(p, __ATOMIC_RELAXED, __HIP_MEMORY_SCOPE_AGENT);
}
__device__ __forceinline__ void a_st(int* p, int v) {
    __hip_atomic_store(p, v, __ATOMIC_RELAXED, __HIP_MEMORY_SCOPE_AGENT);
}
__device__ __forceinline__ int a_add(int* p) {
    return __hip_atomic_fetch_add(p, 1, __ATOMIC_RELAXED, __HIP_MEMORY_SCOPE_AGENT);
}

__device__ __forceinline__ float fsig(float x)  { return 1.f / (1.f + __expf(-x)); }
__device__ __forceinline__ float ftanh(float x) { return 1.f - 2.f / (__expf(2.f * x) + 1.f); }

__global__ __launch_bounds__(512, 1)
void lstm_pair_kernel(const int* __restrict__ path, const int* __restrict__ vlen,
                      const float* __restrict__ emb, const float* __restrict__ Wih,
                      const float* __restrict__ Whh, const float* __restrict__ bih,
                      const float* __restrict__ bhh, float* __restrict__ out,
                      uint32_t* ctl) {
    uint32_t* excF = ctl + WS_EXC;              // sc0 region
    uint32_t* excA = excF + 2 * BB * 128;       // agent fallback region
    const int tid = threadIdx.x;

    // ---- handshake-hardened same-XCD pairing ----
    __shared__ int s_bh;
    if (tid == 0) {
        uint32_t xcc;
        asm volatile("s_getreg_b32 %0, hwreg(20, 0, 4)" : "=s"(xcc));  // HW_REG_XCC_ID
        xcc &= 7;
        int rank  = a_add((int*)&ctl[WS_RANK + xcc]);
        int p     = rank >> 1;
        int half  = rank & 1;
        int batch = BB;
        bool orphan = false;
        if (p < 64) {
            int* hel = (int*)&ctl[WS_HELLO + xcc * 64 + p];
            int* bt  = (int*)&ctl[WS_BTAB  + xcc * 64 + p];
            if (half) {
                a_st(hel, 1);                               // commit to this pair
                int v = 0, w = 1 << 18;
                do { v = a_ld(bt); if (!v) __builtin_amdgcn_s_sleep(2); } while (!v && --w);
                if (v > 0) batch = v - 1;
                else if (v < 0) orphan = true;              // partner gave up on us
            } else {
                int v = 0;
                for (int it = 0; it < 300 && !v; ++it) {    // ~60us: partner hello
                    v = a_ld(hel);
                    if (!v) __builtin_amdgcn_s_sleep(8);
                }
                if (v) { batch = a_add((int*)&ctl[WS_BCNT]); a_st(bt, batch + 1); }
                else   { a_st(bt, -1); orphan = true; }     // no partner on this XCD
            }
        } else orphan = true;
        if (orphan) {                                       // global rescue (count is even)
            int o  = a_add((int*)&ctl[WS_OCNT]);
            int op = o >> 1;
            half   = o & 1;
            batch  = BB;
            if (op < 32) {
                int* ohel = (int*)&ctl[WS_OHELLO + op];
                int* obt  = (int*)&ctl[WS_OBTAB  + op];
                if (half) {
                    a_st(ohel, 1);
                    int v = 0, w = 1 << 18;
                    do { v = a_ld(obt); if (!v) __builtin_amdgcn_s_sleep(2); } while (!v && --w);
                    if (v > 0) batch = v - 1;
                } else {
                    int v = 0, w = 1 << 18;
                    do { v = a_ld(ohel); if (!v) __builtin_amdgcn_s_sleep(2); } while (!v && --w);
                    if (v) { batch = a_add((int*)&ctl[WS_BCNT]); a_st(obt, batch + 1); }
                }
            }
        }
        s_bh = (batch << 1) | half;
    }
    __syncthreads();
    const int b    = s_bh >> 1;
    const int half = s_bh & 1;          // owns h units [128*half, 128*half+128)
    if (b >= BB) return;                // surplus WG

    const int cg = tid & 7;             // col-group: h cols [32cg,+32), x cols [16cg,+16)
    const int rb = tid >> 3;            // row-block 0..63: local gate rows [8rb, 8rb+8)

    __shared__ uint32_t h_pk[8][24];    // full packed h (128 u32 used + pad)
    __shared__ uint32_t x_pk[2][8][12]; // packed x_t, double buffered (64 u32 used + pad)
    __shared__ float    G[512];         // our 512 gate pre-activations
    __shared__ int      path_l[TT];

    // ---- weight slices -> registers: 8 local rows x (16 h-u32 + 8 x-u32) ----
    uint32_t whh[128], wih[64];
#pragma unroll
    for (int rr = 0; rr < 8; ++rr) {
        const int lr   = (rb << 3) + rr;                              // local row 0..511
        const int grow = ((lr >> 7) << 8) + (half << 7) + (lr & 127); // global gate row
        const float* wr = Whh + grow * HH + (cg << 5);
#pragma unroll
        for (int c = 0; c < 16; ++c) whh[rr * 16 + c] = pk_f16(wr[2 * c], wr[2 * c + 1]);
        const float* wr2 = Wih + grow * DD + (cg << 4);
#pragma unroll
        for (int c = 0; c < 8; ++c) wih[rr * 8 + c] = pk_f16(wr2[2 * c], wr2[2 * c + 1]);
    }
    const int L = vlen[b];

    float bi = 0.f, bf = 0.f, bg = 0.f, bo = 0.f;
    if (tid < 128) {
        int u = (half << 7) + tid;
        bi = bih[u]       + bhh[u];
        bf = bih[256 + u] + bhh[256 + u];
        bg = bih[512 + u] + bhh[512 + u];
        bo = bih[768 + u] + bhh[768 + u];
    }
    path_l[tid] = path[b * TT + tid];               // 512 threads == TT
    if (tid < 192) ((uint32_t*)h_pk)[tid] = 0u;     // h_0 = 0 (pads included)
    __syncthreads();

    // x pipeline (waves 6-7): stage x_0, prefetch x_1
    float xr_next = 0.f;
    if (tid >= 384) {
        int e = tid - 384;
        float x0  = emb[(size_t)path_l[0] * DD + e];
        float x0h = __shfl_xor(x0, 1);
        if (!(e & 1)) { int j = e >> 1; x_pk[0][j >> 3][j & 7] = pk_f16(x0, x0h); }
        xr_next = emb[(size_t)path_l[L > 1 ? 1 : 0] * DD + e];
    }
    float c_state = 0.f;
    bool  fast_ok = true;
    __syncthreads();

    for (int t = 0; t < L; ++t) {
        const int slot  = t & 1;
        const int phase = (t >> 1) & 1;
        const uint32_t want = phase ? 0x40004000u : 0u;

        // ---- dots: 8 rows x (32 h + 16 x cols); LDS = 6 x ds_read_b128/thread ----
        const uint4 hv0 = *(const uint4*)&h_pk[cg][0];
        const uint4 hv1 = *(const uint4*)&h_pk[cg][4];
        const uint4 hv2 = *(const uint4*)&h_pk[cg][8];
        const uint4 hv3 = *(const uint4*)&h_pk[cg][12];
        const uint4 xv0 = *(const uint4*)&x_pk[slot][cg][0];
        const uint4 xv1 = *(const uint4*)&x_pk[slot][cg][4];
        float acc[8];
#pragma unroll
        for (int rr = 0; rr < 8; ++rr) {
            float a = 0.f;
            a = dot2(whh[rr * 16 +  0], hv0.x, a);
            a = dot2(whh[rr * 16 +  1], hv0.y, a);
            a = dot2(whh[rr * 16 +  2], hv0.z, a);
            a = dot2(whh[rr * 16 +  3], hv0.w, a);
            a = dot2(whh[rr * 16 +  4], hv1.x, a);
            a = dot2(whh[rr * 16 +  5], hv1.y, a);
            a = dot2(whh[rr * 16 +  6], hv1.z, a);
            a = dot2(whh[rr * 16 +  7], hv1.w, a);
            a = dot2(whh[rr * 16 +  8], hv2.x, a);
            a = dot2(whh[rr * 16 +  9], hv2.y, a);
            a = dot2(whh[rr * 16 + 10], hv2.z, a);
            a = dot2(whh[rr * 16 + 11], hv2.w, a);
            a = dot2(whh[rr * 16 + 12], hv3.x, a);
            a = dot2(whh[rr * 16 + 13], hv3.y, a);
            a = dot2(whh[rr * 16 + 14], hv3.z, a);
            a = dot2(whh[rr * 16 + 15], hv3.w, a);
            a = dot2(wih[rr * 8 + 0], xv0.x, a);
            a = dot2(wih[rr * 8 + 1], xv0.y, a);
            a = dot2(wih[rr * 8 + 2], xv0.z, a);
            a = dot2(wih[rr * 8 + 3], xv0.w, a);
            a = dot2(wih[rr * 8 + 4], xv1.x, a);
            a = dot2(wih[rr * 8 + 5], xv1.y, a);
            a = dot2(wih[rr * 8 + 6], xv1.z, a);
            a = dot2(wih[rr * 8 + 7], xv1.w, a);
            a = dpp_add<0xB1>(a);
            a = dpp_add<0x4E>(a);
            a = dpp_add<0x141>(a);
            acc[rr] = a;
        }
        if (cg == 0) {
            *(float4*)&G[(rb << 3) + 0] = make_float4(acc[0], acc[1], acc[2], acc[3]);
            *(float4*)&G[(rb << 3) + 4] = make_float4(acc[4], acc[5], acc[6], acc[7]);
        }
        __syncthreads();

        // ---- roles: waves0-1 pointwise+publish | wave5 poll | waves6-7 x staging ----
        if (tid < 128) {
            float gi = fsig(G[tid] + bi);
            float gf = fsig(G[128 + tid] + bf);
            float gg = ftanh(G[256 + tid] + bg);
            float go = fsig(G[384 + tid] + bo);
            c_state  = gf * c_state + gi * gg;
            float h  = go * ftanh(c_state);
            if (t == L - 1) out[b * HH + (half << 7) + tid] = h;
            float h1 = __shfl_xor(h, 1);
            if (!(tid & 1)) {
                uint32_t pk = pk_f16(h, h1);
                int j = (half << 6) + (tid >> 1);            // global u32 idx 0..127
                h_pk[j >> 4][j & 15] = pk;                   // own slice via LDS
                uint32_t enc = phase ? ~pk : pk;
                int idx = (slot * BB + b) * 128 + j;
                store_sc0(excF + idx, enc);                  // same-XCD L2 path
                __hip_atomic_store(excA + idx, enc,
                                   __ATOMIC_RELAXED, __HIP_MEMORY_SCOPE_AGENT);
            }
        } else if (tid >= 320 && tid < 384) {
            if (t < L - 1) {
                int c = tid - 320;                           // 64 peer u32s
                int j = ((1 - half) << 6) + c;
                const int idx = (slot * BB + b) * 128 + j;
                uint32_t v; bool got = false;
                if (fast_ok) {
                    int bound = (t == 0) ? 1500 : 400;
                    do {
                        v = load_sc0(excF + idx);
                        got = ((v & 0x40004000u) == want);
                    } while (!got && --bound);
                    if (!got) fast_ok = false;               // permanent fallback
                }
                if (!got) {
                    int spins = 0;
                    do {
                        v = __hip_atomic_load(excA + idx, __ATOMIC_RELAXED,
                                              __HIP_MEMORY_SCOPE_AGENT);
                    } while ((v & 0x40004000u) != want && ++spins < (1 << 20));
                }
                uint32_t d = phase ? ~v : v;
                h_pk[j >> 4][j & 15] = d;
            }
        } else if (tid >= 384) {
            int e = tid - 384;
            float xh = __shfl_xor(xr_next, 1);
            if (!(e & 1)) { int j = e >> 1; x_pk[slot ^ 1][j >> 3][j & 7] = pk_f16(xr_next, xh); }
            int tpf = (t + 2 < TT) ? t + 2 : TT - 1;
            xr_next = emb[(size_t)path_l[tpf] * DD + e];     // prefetch x_{t+2}
        }
        __syncthreads();
    }
}

extern "C" void kernel_launch(void* const* d_in, const int* in_sizes, int n_in,
                              void* d_out, int out_size, void* d_ws, size_t ws_size,
                              hipStream_t stream) {
    const int*   path = (const int*)d_in[0];
    const int*   vlen = (const int*)d_in[1];
    const float* emb  = (const float*)d_in[2];
    const float* Wih  = (const float*)d_in[3];
    const float* Whh  = (const float*)d_in[4];
    const float* bih  = (const float*)d_in[5];
    const float* bhh  = (const float*)d_in[6];

    // control region zeroed; exchange regions 0xFF (bit14 set -> phase-0 reject)
    (void)hipMemsetAsync(d_ws, 0x00, (size_t)WS_EXC * 4, stream);
    (void)hipMemsetAsync((char*)d_ws + (size_t)WS_EXC * 4, 0xFF,
                         (size_t)2 * 2 * BB * 128 * 4, stream);
    lstm_pair_kernel<<<256, 512, 0, stream>>>(path, vlen, emb, Wih, Whh, bih, bhh,
                                              (float*)d_out, (uint32_t*)d_ws);
}